// Round 1
// baseline (518.993 us; speedup 1.0000x reference)
//
#include <hip/hip_runtime.h>

#define NN   8192
#define FIN  128
#define HH   256
#define CAP  128   // max neighbors kept per row; E[deg]~32, P(deg>128) ~ 0

// ---------------------------------------------------------------------------
// Pass over A: build per-row adjacency list, degree-based norm, exposure.
// exposure[i] = t[i] * deg[i] / (deg[i] + 1e-8)   (treatments broadcast over cols)
// dinv[i]     = 1/sqrt(deg[i] + 1)                (A + I self-loop)
// ---------------------------------------------------------------------------
__global__ __launch_bounds__(256) void k_build(
    const float* __restrict__ A, const float* __restrict__ treat,
    int* __restrict__ cols, int* __restrict__ cnt,
    float* __restrict__ dinv, float* __restrict__ expo)
{
  const int row = blockIdx.x;
  const float4* Ar = reinterpret_cast<const float4*>(A + (size_t)row * NN);
  __shared__ int s_cnt;
  __shared__ float s_rs[4];
  if (threadIdx.x == 0) s_cnt = 0;
  __syncthreads();

  float rs = 0.f;
  int* myCols = cols + (size_t)row * CAP;
  #pragma unroll
  for (int it = 0; it < NN / 4 / 256; ++it) {
    const int idx = it * 256 + threadIdx.x;
    const float4 a = Ar[idx];
    const int base = idx * 4;
    const float av[4] = {a.x, a.y, a.z, a.w};
    #pragma unroll
    for (int u = 0; u < 4; ++u) {
      if (av[u] != 0.0f) {
        rs += av[u];
        int p = atomicAdd(&s_cnt, 1);
        if (p < CAP) myCols[p] = base + u;
      }
    }
  }
  // block-wide reduce of rs (4 waves)
  #pragma unroll
  for (int off = 32; off > 0; off >>= 1) rs += __shfl_down(rs, off);
  const int wid = threadIdx.x >> 6;
  if ((threadIdx.x & 63) == 0) s_rs[wid] = rs;
  __syncthreads();
  if (threadIdx.x == 0) {
    const float R = s_rs[0] + s_rs[1] + s_rs[2] + s_rs[3];
    int n = s_cnt; if (n > CAP) n = CAP;
    cnt[row]  = n;
    dinv[row] = rsqrtf(R + 1.0f);
    expo[row] = treat[row] * R / (R + 1e-8f);
  }
}

// ---------------------------------------------------------------------------
// Dense fp32 GEMM  out[M0 x HH] = M[M0 x K] @ W[K x HH]
// tile 128x64, 256 threads (16x16), 8x4 micro-tile, K-panel 16 staged in LDS.
// EXPO: adds exposure column (W row K) + bias + relu  (embedding layer).
// ---------------------------------------------------------------------------
template<int K, bool EXPO>
__global__ __launch_bounds__(256) void k_gemm(
    const float* __restrict__ M, const float* __restrict__ W,
    const float* __restrict__ bias, const float* __restrict__ expo,
    float* __restrict__ out)
{
  constexpr int BM = 128, BN = 64, KT = 16;
  __shared__ float As[KT][BM];
  __shared__ float Bs[KT][BN];
  const int tid = threadIdx.x;
  const int tx = tid & 15;        // output col group (4 cols)
  const int ty = tid >> 4;        // output row group (8 rows)
  const int r0 = blockIdx.x * BM;
  const int c0 = blockIdx.y * BN;

  float acc[8][4];
  #pragma unroll
  for (int i = 0; i < 8; ++i)
    #pragma unroll
    for (int j = 0; j < 4; ++j) acc[i][j] = 0.f;

  const int lr = tid >> 1;          // 0..127: A-tile row loaded by this thread
  const int lk = (tid & 1) * 8;     // 0 or 8: k offset
  const int bk = tid >> 4;          // 0..15:  B-tile k row
  const int bc = (tid & 15) * 4;    // B-tile col

  for (int k0 = 0; k0 < K; k0 += KT) {
    const float4 a0 = *reinterpret_cast<const float4*>(&M[(size_t)(r0 + lr) * K + k0 + lk]);
    const float4 a1 = *reinterpret_cast<const float4*>(&M[(size_t)(r0 + lr) * K + k0 + lk + 4]);
    const float4 b0 = *reinterpret_cast<const float4*>(&W[(size_t)(k0 + bk) * HH + c0 + bc]);
    __syncthreads();   // previous iteration's LDS reads done
    As[lk + 0][lr] = a0.x; As[lk + 1][lr] = a0.y; As[lk + 2][lr] = a0.z; As[lk + 3][lr] = a0.w;
    As[lk + 4][lr] = a1.x; As[lk + 5][lr] = a1.y; As[lk + 6][lr] = a1.z; As[lk + 7][lr] = a1.w;
    *reinterpret_cast<float4*>(&Bs[bk][bc]) = b0;
    __syncthreads();
    #pragma unroll
    for (int kk = 0; kk < KT; ++kk) {
      const float4 av0 = *reinterpret_cast<const float4*>(&As[kk][ty * 8]);
      const float4 av1 = *reinterpret_cast<const float4*>(&As[kk][ty * 8 + 4]);
      const float4 bv  = *reinterpret_cast<const float4*>(&Bs[kk][tx * 4]);
      const float ar[8] = {av0.x, av0.y, av0.z, av0.w, av1.x, av1.y, av1.z, av1.w};
      const float br[4] = {bv.x, bv.y, bv.z, bv.w};
      #pragma unroll
      for (int i = 0; i < 8; ++i)
        #pragma unroll
        for (int j = 0; j < 4; ++j)
          acc[i][j] += ar[i] * br[j];
    }
  }

  float eb[4] = {0, 0, 0, 0}, bs[4] = {0, 0, 0, 0};
  if constexpr (EXPO) {
    const float4 we = *reinterpret_cast<const float4*>(&W[(size_t)K * HH + c0 + tx * 4]); // row K
    eb[0] = we.x; eb[1] = we.y; eb[2] = we.z; eb[3] = we.w;
    const float4 bv = *reinterpret_cast<const float4*>(&bias[c0 + tx * 4]);
    bs[0] = bv.x; bs[1] = bv.y; bs[2] = bv.z; bs[3] = bv.w;
  }
  #pragma unroll
  for (int i = 0; i < 8; ++i) {
    const int r = r0 + ty * 8 + i;
    float4 o;
    float ov[4];
    if constexpr (EXPO) {
      const float e = expo[r];
      #pragma unroll
      for (int j = 0; j < 4; ++j) ov[j] = fmaxf(acc[i][j] + e * eb[j] + bs[j], 0.f);
    } else {
      #pragma unroll
      for (int j = 0; j < 4; ++j) ov[j] = acc[i][j];
    }
    o.x = ov[0]; o.y = ov[1]; o.z = ov[2]; o.w = ov[3];
    *reinterpret_cast<float4*>(&out[(size_t)r * HH + c0 + tx * 4]) = o;
  }
}

// ---------------------------------------------------------------------------
// Sparse aggregation:  out[i,:] = relu( dinv[i]*( sum_{j in nbr(i)} dinv[j]*M[j,:]
//                                                + dinv[i]*M[i,:] ) + b )
// one block per node, thread = one feature column.
// ---------------------------------------------------------------------------
__global__ __launch_bounds__(256) void k_agg(
    const float* __restrict__ M,
    const int* __restrict__ cols, const int* __restrict__ cnt,
    const float* __restrict__ dinv, const float* __restrict__ bias,
    float* __restrict__ out)
{
  const int i = blockIdx.x;
  const int c = threadIdx.x;
  __shared__ int   s_cols[CAP];
  __shared__ float s_w[CAP];
  const int n = cnt[i];
  for (int t = threadIdx.x; t < n; t += 256) {
    const int j = cols[(size_t)i * CAP + t];
    s_cols[t] = j;
    s_w[t] = dinv[j];
  }
  __syncthreads();
  const float di = dinv[i];
  float acc = di * M[(size_t)i * HH + c];
  #pragma unroll 4
  for (int t = 0; t < n; ++t)
    acc += s_w[t] * M[(size_t)s_cols[t] * HH + c];
  const float v = di * acc + bias[c];
  out[(size_t)i * HH + c] = fmaxf(v, 0.f);
}

// ---------------------------------------------------------------------------
// Heads: y0 = emb @ W_t0 + b_t0 ; y1 = emb @ W_t1 + b_t1.  One wave per row.
// ---------------------------------------------------------------------------
__global__ __launch_bounds__(64) void k_heads(
    const float* __restrict__ emb,
    const float* __restrict__ Wt0, const float* __restrict__ bt0,
    const float* __restrict__ Wt1, const float* __restrict__ bt1,
    float* __restrict__ y0, float* __restrict__ y1)
{
  const int i = blockIdx.x;
  const int l = threadIdx.x;
  float s0 = 0.f, s1 = 0.f;
  #pragma unroll
  for (int c = l; c < HH; c += 64) {
    const float e = emb[(size_t)i * HH + c];
    s0 += e * Wt0[c];
    s1 += e * Wt1[c];
  }
  #pragma unroll
  for (int off = 32; off > 0; off >>= 1) {
    s0 += __shfl_down(s0, off);
    s1 += __shfl_down(s1, off);
  }
  if (l == 0) {
    y0[i] = s0 + bt0[0];
    y1[i] = s1 + bt1[0];
  }
}

// ---------------------------------------------------------------------------
extern "C" void kernel_launch(void* const* d_in, const int* in_sizes, int n_in,
                              void* d_out, int out_size, void* d_ws, size_t ws_size,
                              hipStream_t stream)
{
  const float* A      = (const float*)d_in[0];
  const float* feats  = (const float*)d_in[1];
  const float* treat  = (const float*)d_in[2];
  const float* W1     = (const float*)d_in[3];
  const float* b1     = (const float*)d_in[4];
  const float* W2     = (const float*)d_in[5];
  const float* b2     = (const float*)d_in[6];
  const float* W_emb  = (const float*)d_in[7];
  const float* b_emb  = (const float*)d_in[8];
  const float* W_t0   = (const float*)d_in[9];
  const float* b_t0   = (const float*)d_in[10];
  const float* W_t1   = (const float*)d_in[11];
  const float* b_t1   = (const float*)d_in[12];
  float* dout = (float*)d_out;

  // workspace layout (~20.2 MiB)
  int*   cols = (int*)d_ws;                 // NN*CAP ints
  int*   cnt  = cols + (size_t)NN * CAP;    // NN
  float* dinv = (float*)(cnt + NN);         // NN
  float* expo = dinv + NN;                  // NN
  float* bufA = expo + NN;                  // NN*HH
  float* bufB = bufA + (size_t)NN * HH;     // NN*HH

  float* y0  = dout;
  float* y1  = dout + NN;
  float* emb = dout + 2 * NN;

  const dim3 gemmGrid(NN / 128, HH / 64);

  // 1. scan A: adjacency lists + norm + exposure
  k_build<<<NN, 256, 0, stream>>>(A, treat, cols, cnt, dinv, expo);
  // 2. XW1 = features @ W1
  k_gemm<FIN, false><<<gemmGrid, 256, 0, stream>>>(feats, W1, nullptr, nullptr, bufA);
  // 3. h1 = relu(nA @ XW1 + b1)
  k_agg<<<NN, 256, 0, stream>>>(bufA, cols, cnt, dinv, b1, bufB);
  // 4. h1W2 = h1 @ W2
  k_gemm<HH, false><<<gemmGrid, 256, 0, stream>>>(bufB, W2, nullptr, nullptr, bufA);
  // 5. h2 = relu(nA @ h1W2 + b2)
  k_agg<<<NN, 256, 0, stream>>>(bufA, cols, cnt, dinv, b2, bufB);
  // 6. emb = relu([h2, expo] @ W_emb + b_emb)   (written straight to d_out)
  k_gemm<HH, true><<<gemmGrid, 256, 0, stream>>>(bufB, W_emb, b_emb, expo, emb);
  // 7. y0, y1 heads
  k_heads<<<NN, 64, 0, stream>>>(emb, W_t0, b_t0, W_t1, b_t1, y0, y1);
}

// Round 2
// 458.396 us; speedup vs baseline: 1.1322x; 1.1322x over previous
//
#include <hip/hip_runtime.h>

#define NN   8192
#define FIN  128
#define HH   256
#define CAP  128   // max neighbors kept per row; E[deg]~32, max ~70, P(>128) ~ 0

typedef float f32x4 __attribute__((ext_vector_type(4)));

__device__ __forceinline__ const f32x4* c4(const float* p) { return (const f32x4*)p; }
__device__ __forceinline__       f32x4* p4(float* p)       { return (f32x4*)p; }

// ---------------------------------------------------------------------------
// Build body: one block scans one row of A (nontemporal — read-once stream).
// cols/cnt: adjacency list; dinv = 1/sqrt(deg+1); expo = t*deg/(deg+1e-8).
// ---------------------------------------------------------------------------
__device__ __forceinline__ void build_body(
    int row, const float* __restrict__ A, const float* __restrict__ treat,
    int* __restrict__ cols, int* __restrict__ cnt,
    float* __restrict__ dinv, float* __restrict__ expo,
    int* s_cnt, float* s_rs)
{
  const f32x4* Ar = c4(A + (size_t)row * NN);
  if (threadIdx.x == 0) *s_cnt = 0;
  __syncthreads();

  float rs = 0.f;
  int* myCols = cols + (size_t)row * CAP;
  #pragma unroll
  for (int it = 0; it < NN / 4 / 256; ++it) {
    const int idx = it * 256 + threadIdx.x;
    const f32x4 a = __builtin_nontemporal_load(Ar + idx);
    const int base = idx * 4;
    #pragma unroll
    for (int u = 0; u < 4; ++u) {
      if (a[u] != 0.0f) {
        rs += a[u];
        int p = atomicAdd(s_cnt, 1);
        if (p < CAP) myCols[p] = base + u;
      }
    }
  }
  #pragma unroll
  for (int off = 32; off > 0; off >>= 1) rs += __shfl_down(rs, off);
  const int wid = threadIdx.x >> 6;
  if ((threadIdx.x & 63) == 0) s_rs[wid] = rs;
  __syncthreads();
  if (threadIdx.x == 0) {
    const float R = s_rs[0] + s_rs[1] + s_rs[2] + s_rs[3];
    int n = *s_cnt; if (n > CAP) n = CAP;
    cnt[row]  = n;
    dinv[row] = rsqrtf(R + 1.0f);
    expo[row] = treat[row] * R / (R + 1e-8f);
  }
}

// ---------------------------------------------------------------------------
// GEMM body: out[8192 x HH] = M[8192 x K] @ W[K x HH]
// 64x64 tile, 256 threads, 4x4 micro-tile, KT=16 LDS panels with register
// prefetch of the next panel (global latency hidden under FMA loop).
// EXPO: + expo[r]*W[K][c] + bias, relu.  HEADS: fused y0/y1 partial dots.
// ---------------------------------------------------------------------------
template<int K, bool EXPO, bool HEADS>
__device__ __forceinline__ void gemm_body(
    int bidx,
    const float* __restrict__ M, const float* __restrict__ W,
    const float* __restrict__ bias, const float* __restrict__ expo,
    const float* __restrict__ Wt0, const float* __restrict__ Wt1,
    float* __restrict__ out, float* __restrict__ y0, float* __restrict__ y1,
    float (*As)[64], float (*Bs)[64])
{
  const int tid = threadIdx.x;
  const int tx = tid & 15, ty = tid >> 4;
  const int bx = bidx & 127, by = bidx >> 7;
  const int r0 = bx * 64, c0 = by * 64;
  const int la_r = tid & 63;          // A row within tile
  const int la_k = (tid >> 6) << 2;   // A k offset: 0,4,8,12
  const int lb_k = tid >> 4;          // B k row 0..15
  const int lb_c = (tid & 15) << 2;   // B col offset

  const float* Abase = M + (size_t)(r0 + la_r) * K + la_k;
  const float* Bbase = W + (size_t)lb_k * HH + c0 + lb_c;

  f32x4 aR = *c4(Abase);
  f32x4 bR = *c4(Bbase);
  float acc[4][4] = {};

  #pragma unroll 1
  for (int k0 = 0; k0 < K; k0 += 16) {
    As[la_k + 0][la_r] = aR[0];
    As[la_k + 1][la_r] = aR[1];
    As[la_k + 2][la_r] = aR[2];
    As[la_k + 3][la_r] = aR[3];
    *p4(&Bs[lb_k][lb_c]) = bR;
    __syncthreads();
    if (k0 + 16 < K) {                       // prefetch next panel into regs
      aR = *c4(Abase + k0 + 16);
      bR = *c4(Bbase + (size_t)(k0 + 16) * HH);
    }
    #pragma unroll
    for (int kk = 0; kk < 16; ++kk) {
      const f32x4 av = *c4(&As[kk][ty * 4]);
      const f32x4 bv = *c4(&Bs[kk][tx * 4]);
      #pragma unroll
      for (int i = 0; i < 4; ++i)
        #pragma unroll
        for (int j = 0; j < 4; ++j)
          acc[i][j] += av[i] * bv[j];
    }
    __syncthreads();
  }

  f32x4 eb = {0.f, 0.f, 0.f, 0.f}, bs = {0.f, 0.f, 0.f, 0.f};
  if constexpr (EXPO) {
    eb = *c4(&W[(size_t)K * HH + c0 + tx * 4]);   // exposure row of W_emb
    bs = *c4(&bias[c0 + tx * 4]);
  }
  f32x4 wt0 = {0.f, 0.f, 0.f, 0.f}, wt1 = {0.f, 0.f, 0.f, 0.f};
  if constexpr (HEADS) {
    wt0 = *c4(&Wt0[c0 + tx * 4]);
    wt1 = *c4(&Wt1[c0 + tx * 4]);
  }
  #pragma unroll
  for (int i = 0; i < 4; ++i) {
    const int r = r0 + ty * 4 + i;
    f32x4 o;
    if constexpr (EXPO) {
      const float e = expo[r];
      #pragma unroll
      for (int j = 0; j < 4; ++j) o[j] = fmaxf(acc[i][j] + e * eb[j] + bs[j], 0.f);
    } else {
      #pragma unroll
      for (int j = 0; j < 4; ++j) o[j] = acc[i][j];
    }
    *p4(&out[(size_t)r * HH + c0 + tx * 4]) = o;
    if constexpr (HEADS) {
      float s0 = o[0] * wt0[0] + o[1] * wt0[1] + o[2] * wt0[2] + o[3] * wt0[3];
      float s1 = o[0] * wt1[0] + o[1] * wt1[1] + o[2] * wt1[2] + o[3] * wt1[3];
      #pragma unroll
      for (int off = 8; off > 0; off >>= 1) {
        s0 += __shfl_down(s0, off);
        s1 += __shfl_down(s1, off);
      }
      if ((tid & 15) == 0) {
        atomicAdd(&y0[r], s0);
        atomicAdd(&y1[r], s1);
      }
    }
  }
}

// ---------------------------------------------------------------------------
// Fused: blocks 0..511 do gemm1 (feats @ W1), blocks 512..8703 scan A.
// GEMM blocks first so they co-schedule under the BW-bound A scan.
// ---------------------------------------------------------------------------
__global__ __launch_bounds__(256) void k_build_gemm1(
    const float* __restrict__ A, const float* __restrict__ treat,
    const float* __restrict__ feats, const float* __restrict__ W1,
    int* __restrict__ cols, int* __restrict__ cnt,
    float* __restrict__ dinv, float* __restrict__ expo,
    float* __restrict__ bufA)
{
  __shared__ float As[16][64];
  __shared__ float Bs[16][64];
  __shared__ int   s_cnt;
  __shared__ float s_rs[4];
  const int b = blockIdx.x;
  if (b < 512) {
    gemm_body<FIN, false, false>(b, feats, W1, nullptr, nullptr, nullptr, nullptr,
                                 bufA, nullptr, nullptr, As, Bs);
  } else {
    build_body(b - 512, A, treat, cols, cnt, dinv, expo, &s_cnt, s_rs);
  }
}

template<int K, bool EXPO, bool HEADS>
__global__ __launch_bounds__(256) void k_gemm(
    const float* __restrict__ M, const float* __restrict__ W,
    const float* __restrict__ bias, const float* __restrict__ expo,
    const float* __restrict__ Wt0, const float* __restrict__ Wt1,
    float* __restrict__ out, float* __restrict__ y0, float* __restrict__ y1)
{
  __shared__ float As[16][64];
  __shared__ float Bs[16][64];
  gemm_body<K, EXPO, HEADS>(blockIdx.x, M, W, bias, expo, Wt0, Wt1, out, y0, y1, As, Bs);
}

// ---------------------------------------------------------------------------
// Sparse aggregation, wave-per-node, float4 rows:
// out[i,:] = relu(dinv[i]*(sum_j dinv[j]*M[j,:] + dinv[i]*M[i,:]) + b)
// INIT: also initialize y0/y1 with head biases (before heads' atomics).
// ---------------------------------------------------------------------------
template<bool INIT>
__global__ __launch_bounds__(256) void k_agg(
    const float* __restrict__ M,
    const int* __restrict__ cols, const int* __restrict__ cnt,
    const float* __restrict__ dinv, const float* __restrict__ bias,
    float* __restrict__ out,
    float* __restrict__ dout, const float* __restrict__ bt0, const float* __restrict__ bt1)
{
  const int wid  = threadIdx.x >> 6;
  const int lane = threadIdx.x & 63;
  const int i    = blockIdx.x * 4 + wid;
  __shared__ int   s_cols[4][CAP];
  __shared__ float s_w[4][CAP];

  if constexpr (INIT) {
    if (blockIdx.x < 64) {
      const int idx = blockIdx.x * 256 + threadIdx.x;   // covers 16384 = y0,y1
      dout[idx] = (idx < NN) ? bt0[0] : bt1[0];
    }
  }

  const int n = cnt[i];
  if (lane < n) {
    const int j = cols[(size_t)i * CAP + lane];
    s_cols[wid][lane] = j;  s_w[wid][lane] = dinv[j];
  }
  if (lane + 64 < n) {
    const int j = cols[(size_t)i * CAP + lane + 64];
    s_cols[wid][lane + 64] = j;  s_w[wid][lane + 64] = dinv[j];
  }
  __syncthreads();

  const float di = dinv[i];
  const f32x4 bias4 = *c4(&bias[lane * 4]);
  f32x4 acc = *c4(&M[(size_t)i * HH + lane * 4]);
  acc *= di;                                   // self-loop term
  #pragma unroll 4
  for (int t = 0; t < n; ++t) {
    const int   j = s_cols[wid][t];
    const float w = s_w[wid][t];
    const f32x4 v = *c4(&M[(size_t)j * HH + lane * 4]);
    acc += w * v;
  }
  f32x4 o = di * acc + bias4;
  #pragma unroll
  for (int q = 0; q < 4; ++q) o[q] = fmaxf(o[q], 0.f);
  *p4(&out[(size_t)i * HH + lane * 4]) = o;
}

// ---------------------------------------------------------------------------
extern "C" void kernel_launch(void* const* d_in, const int* in_sizes, int n_in,
                              void* d_out, int out_size, void* d_ws, size_t ws_size,
                              hipStream_t stream)
{
  const float* A      = (const float*)d_in[0];
  const float* feats  = (const float*)d_in[1];
  const float* treat  = (const float*)d_in[2];
  const float* W1     = (const float*)d_in[3];
  const float* b1     = (const float*)d_in[4];
  const float* W2     = (const float*)d_in[5];
  const float* b2     = (const float*)d_in[6];
  const float* W_emb  = (const float*)d_in[7];
  const float* b_emb  = (const float*)d_in[8];
  const float* W_t0   = (const float*)d_in[9];
  const float* b_t0   = (const float*)d_in[10];
  const float* W_t1   = (const float*)d_in[11];
  const float* b_t1   = (const float*)d_in[12];
  float* dout = (float*)d_out;

  // workspace layout (~20.2 MiB, all 16B-aligned)
  int*   cols = (int*)d_ws;                 // NN*CAP ints (4 MiB)
  int*   cnt  = cols + (size_t)NN * CAP;    // NN
  float* dinv = (float*)(cnt + NN);         // NN
  float* expo = dinv + NN;                  // NN
  float* bufA = expo + NN;                  // NN*HH
  float* bufB = bufA + (size_t)NN * HH;     // NN*HH

  float* y0  = dout;
  float* y1  = dout + NN;
  float* emb = dout + 2 * NN;

  // 1. fused: A scan (adjacency+norm+exposure) || XW1 = feats @ W1
  k_build_gemm1<<<8704, 256, 0, stream>>>(A, treat, feats, W1, cols, cnt, dinv, expo, bufA);
  // 2. h1 = relu(nA @ XW1 + b1)
  k_agg<false><<<NN / 4, 256, 0, stream>>>(bufA, cols, cnt, dinv, b1, bufB,
                                           nullptr, nullptr, nullptr);
  // 3. h1W2 = h1 @ W2
  k_gemm<HH, false, false><<<512, 256, 0, stream>>>(bufB, W2, nullptr, nullptr,
                                                    nullptr, nullptr, bufA, nullptr, nullptr);
  // 4. h2 = relu(nA @ h1W2 + b2)  (+ init y0/y1 with head biases)
  k_agg<true><<<NN / 4, 256, 0, stream>>>(bufA, cols, cnt, dinv, b2, bufB,
                                          dout, b_t0, b_t1);
  // 5. emb = relu([h2, expo] @ W_emb + b_emb) -> d_out, with fused y0/y1 heads
  k_gemm<HH, true, true><<<512, 256, 0, stream>>>(bufB, W_emb, b_emb, expo,
                                                  W_t0, W_t1, emb, y0, y1);
}

// Round 4
// 440.954 us; speedup vs baseline: 1.1770x; 1.0396x over previous
//
#include <hip/hip_runtime.h>

#define NN   8192
#define FIN  128
#define HH   256
#define CAP  128   // max neighbors kept per row; E[deg]~32, max ~70, P(>128) ~ 0

typedef float f32x4 __attribute__((ext_vector_type(4)));
typedef float f32x2 __attribute__((ext_vector_type(2)));

__device__ __forceinline__ const f32x4* c4(const float* p) { return (const f32x4*)p; }
__device__ __forceinline__       f32x4* p4(float* p)       { return (f32x4*)p; }
__device__ __forceinline__ const f32x2* c2(const float* p) { return (const f32x2*)p; }
__device__ __forceinline__       f32x2* p2(float* p)       { return (f32x2*)p; }

// ---------------------------------------------------------------------------
// One block scans one row of A (nontemporal — read-once stream).
// cols/cnt: adjacency list; dinv = 1/sqrt(deg+1); expo = t*deg/(deg+1e-8).
// ---------------------------------------------------------------------------
__global__ __launch_bounds__(256) void k_build(
    const float* __restrict__ A, const float* __restrict__ treat,
    int* __restrict__ cols, int* __restrict__ cnt,
    float* __restrict__ dinv, float* __restrict__ expo)
{
  const int row = blockIdx.x;
  const f32x4* Ar = c4(A + (size_t)row * NN);
  __shared__ int   s_cnt;
  __shared__ float s_rs[4];
  if (threadIdx.x == 0) s_cnt = 0;
  __syncthreads();

  float rs = 0.f;
  int* myCols = cols + (size_t)row * CAP;
  #pragma unroll
  for (int it = 0; it < NN / 4 / 256; ++it) {
    const int idx = it * 256 + threadIdx.x;
    const f32x4 a = __builtin_nontemporal_load(Ar + idx);
    const int base = idx * 4;
    #pragma unroll
    for (int u = 0; u < 4; ++u) {
      if (a[u] != 0.0f) {
        rs += a[u];
        int p = atomicAdd(&s_cnt, 1);
        if (p < CAP) myCols[p] = base + u;
      }
    }
  }
  #pragma unroll
  for (int off = 32; off > 0; off >>= 1) rs += __shfl_down(rs, off);
  const int wid = threadIdx.x >> 6;
  if ((threadIdx.x & 63) == 0) s_rs[wid] = rs;
  __syncthreads();
  if (threadIdx.x == 0) {
    const float R = s_rs[0] + s_rs[1] + s_rs[2] + s_rs[3];
    int n = s_cnt; if (n > CAP) n = CAP;
    cnt[row]  = n;
    dinv[row] = rsqrtf(R + 1.0f);
    expo[row] = treat[row] * R / (R + 1e-8f);
  }
}

// ---------------------------------------------------------------------------
// Sparse aggregation on 128-wide X (layer-1 reorder, no bias/relu):
//   out[i,:] = dinv[i]*( sum_j dinv[j]*X[j,:] + dinv[i]*X[i,:] )
// wave per node, f32x2 per lane (512 B per row gather).
// ---------------------------------------------------------------------------
__global__ __launch_bounds__(256) void k_agg0(
    const float* __restrict__ X,
    const int* __restrict__ cols, const int* __restrict__ cnt,
    const float* __restrict__ dinv, float* __restrict__ out)
{
  const int wid  = threadIdx.x >> 6;
  const int lane = threadIdx.x & 63;
  const int i    = blockIdx.x * 4 + wid;
  __shared__ int   s_cols[4][CAP];
  __shared__ float s_w[4][CAP];

  const int n = cnt[i];
  if (lane < n) {
    const int j = cols[(size_t)i * CAP + lane];
    s_cols[wid][lane] = j;  s_w[wid][lane] = dinv[j];
  }
  if (lane + 64 < n) {
    const int j = cols[(size_t)i * CAP + lane + 64];
    s_cols[wid][lane + 64] = j;  s_w[wid][lane + 64] = dinv[j];
  }
  __syncthreads();

  const float di = dinv[i];
  f32x2 acc = *c2(&X[(size_t)i * FIN + lane * 2]);
  acc *= di;                                   // self-loop term
  #pragma unroll 4
  for (int t = 0; t < n; ++t) {
    const int   j = s_cols[wid][t];
    const float w = s_w[wid][t];
    acc += w * (*c2(&X[(size_t)j * FIN + lane * 2]));
  }
  *p2(&out[(size_t)i * FIN + lane * 2]) = di * acc;
}

// ---------------------------------------------------------------------------
// GEMM body: out[8192 x HH] = M[8192 x K] @ W[K x HH]
// 64x64 tile, 256 threads, 4x4 micro-tile, KT=16 LDS panels with register
// prefetch.  RELU: +bias, relu.  EXPO: + expo[r]*W[K][c] (implies RELU).
// HEADS: fused y0/y1 partial dots via shfl + atomics.
// ---------------------------------------------------------------------------
template<int K, bool RELU, bool EXPO, bool HEADS>
__device__ __forceinline__ void gemm_body(
    int bidx,
    const float* __restrict__ M, const float* __restrict__ W,
    const float* __restrict__ bias, const float* __restrict__ expo,
    const float* __restrict__ Wt0, const float* __restrict__ Wt1,
    float* __restrict__ out, float* __restrict__ y0, float* __restrict__ y1,
    float (*As)[64], float (*Bs)[64])
{
  const int tid = threadIdx.x;
  const int tx = tid & 15, ty = tid >> 4;
  const int bx = bidx & 127, by = bidx >> 7;
  const int r0 = bx * 64, c0 = by * 64;
  const int la_r = tid & 63;          // A row within tile
  const int la_k = (tid >> 6) << 2;   // A k offset: 0,4,8,12
  const int lb_k = tid >> 4;          // B k row 0..15
  const int lb_c = (tid & 15) << 2;   // B col offset

  const float* Abase = M + (size_t)(r0 + la_r) * K + la_k;
  const float* Bbase = W + (size_t)lb_k * HH + c0 + lb_c;

  f32x4 aR = *c4(Abase);
  f32x4 bR = *c4(Bbase);
  float acc[4][4] = {};

  #pragma unroll 1
  for (int k0 = 0; k0 < K; k0 += 16) {
    As[la_k + 0][la_r] = aR[0];
    As[la_k + 1][la_r] = aR[1];
    As[la_k + 2][la_r] = aR[2];
    As[la_k + 3][la_r] = aR[3];
    *p4(&Bs[lb_k][lb_c]) = bR;
    __syncthreads();
    if (k0 + 16 < K) {                       // prefetch next panel into regs
      aR = *c4(Abase + k0 + 16);
      bR = *c4(Bbase + (size_t)(k0 + 16) * HH);
    }
    #pragma unroll
    for (int kk = 0; kk < 16; ++kk) {
      const f32x4 av = *c4(&As[kk][ty * 4]);
      const f32x4 bv = *c4(&Bs[kk][tx * 4]);
      #pragma unroll
      for (int i = 0; i < 4; ++i)
        #pragma unroll
        for (int j = 0; j < 4; ++j)
          acc[i][j] += av[i] * bv[j];
    }
    __syncthreads();
  }

  f32x4 eb = {0.f, 0.f, 0.f, 0.f}, bs = {0.f, 0.f, 0.f, 0.f};
  if constexpr (RELU) bs = *c4(&bias[c0 + tx * 4]);
  if constexpr (EXPO) eb = *c4(&W[(size_t)K * HH + c0 + tx * 4]);  // exposure row
  f32x4 wt0 = {0.f, 0.f, 0.f, 0.f}, wt1 = {0.f, 0.f, 0.f, 0.f};
  if constexpr (HEADS) {
    wt0 = *c4(&Wt0[c0 + tx * 4]);
    wt1 = *c4(&Wt1[c0 + tx * 4]);
  }
  #pragma unroll
  for (int i = 0; i < 4; ++i) {
    const int r = r0 + ty * 4 + i;
    f32x4 o;
    if constexpr (RELU) {
      float e = 0.f;
      if constexpr (EXPO) e = expo[r];
      #pragma unroll
      for (int j = 0; j < 4; ++j) {
        float v = acc[i][j] + bs[j];
        if constexpr (EXPO) v += e * eb[j];
        o[j] = fmaxf(v, 0.f);
      }
    } else {
      #pragma unroll
      for (int j = 0; j < 4; ++j) o[j] = acc[i][j];
    }
    *p4(&out[(size_t)r * HH + c0 + tx * 4]) = o;
    if constexpr (HEADS) {
      float s0 = o[0] * wt0[0] + o[1] * wt0[1] + o[2] * wt0[2] + o[3] * wt0[3];
      float s1 = o[0] * wt1[0] + o[1] * wt1[1] + o[2] * wt1[2] + o[3] * wt1[3];
      #pragma unroll
      for (int off = 8; off > 0; off >>= 1) {
        s0 += __shfl_down(s0, off);
        s1 += __shfl_down(s1, off);
      }
      if ((tid & 15) == 0) {
        atomicAdd(&y0[r], s0);
        atomicAdd(&y1[r], s1);
      }
    }
  }
}

template<int K, bool RELU, bool EXPO, bool HEADS>
__global__ __launch_bounds__(256) void k_gemm(
    const float* __restrict__ M, const float* __restrict__ W,
    const float* __restrict__ bias, const float* __restrict__ expo,
    const float* __restrict__ Wt0, const float* __restrict__ Wt1,
    float* __restrict__ out, float* __restrict__ y0, float* __restrict__ y1)
{
  __shared__ float As[16][64];
  __shared__ float Bs[16][64];
  gemm_body<K, RELU, EXPO, HEADS>(blockIdx.x, M, W, bias, expo, Wt0, Wt1,
                                  out, y0, y1, As, Bs);
}

// ---------------------------------------------------------------------------
// Sparse aggregation on 256-wide M (layer 2), wave-per-node, float4 rows:
// out[i,:] = relu(dinv[i]*(sum_j dinv[j]*M[j,:] + dinv[i]*M[i,:]) + b)
// INIT: also initialize y0/y1 with head biases (before heads' atomics).
// ---------------------------------------------------------------------------
template<bool INIT>
__global__ __launch_bounds__(256) void k_agg(
    const float* __restrict__ M,
    const int* __restrict__ cols, const int* __restrict__ cnt,
    const float* __restrict__ dinv, const float* __restrict__ bias,
    float* __restrict__ out,
    float* __restrict__ dout, const float* __restrict__ bt0, const float* __restrict__ bt1)
{
  const int wid  = threadIdx.x >> 6;
  const int lane = threadIdx.x & 63;
  const int i    = blockIdx.x * 4 + wid;
  __shared__ int   s_cols[4][CAP];
  __shared__ float s_w[4][CAP];

  if constexpr (INIT) {
    if (blockIdx.x < 64) {
      const int idx = blockIdx.x * 256 + threadIdx.x;   // 16384 = y0,y1
      dout[idx] = (idx < NN) ? bt0[0] : bt1[0];
    }
  }

  const int n = cnt[i];
  if (lane < n) {
    const int j = cols[(size_t)i * CAP + lane];
    s_cols[wid][lane] = j;  s_w[wid][lane] = dinv[j];
  }
  if (lane + 64 < n) {
    const int j = cols[(size_t)i * CAP + lane + 64];
    s_cols[wid][lane + 64] = j;  s_w[wid][lane + 64] = dinv[j];
  }
  __syncthreads();

  const float di = dinv[i];
  const f32x4 bias4 = *c4(&bias[lane * 4]);
  f32x4 acc = *c4(&M[(size_t)i * HH + lane * 4]);
  acc *= di;                                   // self-loop term
  #pragma unroll 4
  for (int t = 0; t < n; ++t) {
    const int   j = s_cols[wid][t];
    const float w = s_w[wid][t];
    acc += w * (*c4(&M[(size_t)j * HH + lane * 4]));
  }
  f32x4 o = di * acc + bias4;
  #pragma unroll
  for (int q = 0; q < 4; ++q) o[q] = fmaxf(o[q], 0.f);
  *p4(&out[(size_t)i * HH + lane * 4]) = o;
}

// ---------------------------------------------------------------------------
extern "C" void kernel_launch(void* const* d_in, const int* in_sizes, int n_in,
                              void* d_out, int out_size, void* d_ws, size_t ws_size,
                              hipStream_t stream)
{
  const float* A      = (const float*)d_in[0];
  const float* feats  = (const float*)d_in[1];
  const float* treat  = (const float*)d_in[2];
  const float* W1     = (const float*)d_in[3];
  const float* b1     = (const float*)d_in[4];
  const float* W2     = (const float*)d_in[5];
  const float* b2     = (const float*)d_in[6];
  const float* W_emb  = (const float*)d_in[7];
  const float* b_emb  = (const float*)d_in[8];
  const float* W_t0   = (const float*)d_in[9];
  const float* b_t0   = (const float*)d_in[10];
  const float* W_t1   = (const float*)d_in[11];
  const float* b_t1   = (const float*)d_in[12];
  float* dout = (float*)d_out;

  // workspace layout (~24 MiB, all 16B-aligned)
  int*   cols = (int*)d_ws;                 // NN*CAP ints (4 MiB)
  int*   cnt  = cols + (size_t)NN * CAP;    // NN
  float* dinv = (float*)(cnt + NN);         // NN
  float* expo = dinv + NN;                  // NN
  float* bufX = expo + NN;                  // NN*FIN (4 MiB)
  float* bufA = bufX + (size_t)NN * FIN;    // NN*HH  (8 MiB)
  float* bufB = bufA + (size_t)NN * HH;     // NN*HH  (8 MiB)

  float* y0  = dout;
  float* y1  = dout + NN;
  float* emb = dout + 2 * NN;

  // 1. A scan: adjacency + norm + exposure
  k_build<<<NN, 256, 0, stream>>>(A, treat, cols, cnt, dinv, expo);
  // 2. aggX = nA @ X   (128-wide gather — half the volume of 256-wide)
  k_agg0<<<NN / 4, 256, 0, stream>>>(feats, cols, cnt, dinv, bufX);
  // 3. h1 = relu(aggX @ W1 + b1)
  k_gemm<FIN, true, false, false><<<512, 256, 0, stream>>>(
      bufX, W1, b1, nullptr, nullptr, nullptr, bufB, nullptr, nullptr);
  // 4. h1W2 = h1 @ W2
  k_gemm<HH, false, false, false><<<512, 256, 0, stream>>>(
      bufB, W2, nullptr, nullptr, nullptr, nullptr, bufA, nullptr, nullptr);
  // 5. h2 = relu(nA @ h1W2 + b2)  (+ init y0/y1 with head biases)
  k_agg<true><<<NN / 4, 256, 0, stream>>>(bufA, cols, cnt, dinv, b2, bufB,
                                          dout, b_t0, b_t1);
  // 6. emb = relu([h2, expo] @ W_emb + b_emb) -> d_out, fused y0/y1 heads
  k_gemm<HH, true, true, true><<<512, 256, 0, stream>>>(
      bufB, W_emb, b_emb, expo, W_t0, W_t1, emb, y0, y1);
}